// Round 13
// baseline (1215.607 us; speedup 1.0000x reference)
//
#include <hip/hip_runtime.h>
#include <hip/hip_bf16.h>

// MultiAttention: S=1024, B=8, D=1024, H=8
// Round 13: counted-lgkmcnt group schedule. Per K-tile: issue ALL 24 fragment
// ds_reads up front (order pinned), lgkmcnt(12)->MFMA0, lgkmcnt(8)->MFMA1,
// mid SBAR (B reads done -> restage this-buf B), lgkmcnt(0)->MFMA2,3, VMC4,
// SBAR. 2 barriers/K-tile (was 8); reads 13-24 hidden under MFMA0-1.
// Epilogues/dataflow identical to round 12. ws peak ~338 MiB.

typedef __attribute__((ext_vector_type(8))) __bf16 bf16x8;
typedef __attribute__((ext_vector_type(4))) float f32x4;

__device__ __forceinline__ unsigned short f2bf(float f) {
  union { float f; unsigned u; } x; x.f = f;
  unsigned r = x.u + 0x7fffu + ((x.u >> 16) & 1u);   // RNE
  return (unsigned short)(r >> 16);
}
__device__ __forceinline__ float bf2f(unsigned short u) {
  union { unsigned u; float f; } x; x.u = ((unsigned)u) << 16;
  return x.f;
}

__device__ __forceinline__ void gload16(const void* g, void* l) {
  __builtin_amdgcn_global_load_lds(
      (const __attribute__((address_space(1))) void*)g,
      (__attribute__((address_space(3))) void*)l, 16, 0, 0);
}

#define SB()    __builtin_amdgcn_sched_barrier(0)
#define SBAR()  do { SB(); __builtin_amdgcn_s_barrier(); SB(); } while (0)
#define LGKMC(n) do { asm volatile("s_waitcnt lgkmcnt(" #n ")" ::: "memory"); SB(); } while (0)
#define VMC4()  do { asm volatile("s_waitcnt vmcnt(4)" ::: "memory"); SB(); } while (0)

// ================= 256x256 8-phase NT GEMM (counted-lgkm groups) ==============
struct Frags { bf16x8 aF[4][2]; bf16x8 aG[4][2]; bf16x8 b0F[2][2]; bf16x8 b1F[2][2]; };

__device__ __forceinline__ void qrA0(const char* sm, int bb, int aRow,
                                     int kx0, int kx1, Frags& fr)
{
#pragma unroll
  for (int m = 0; m < 4; ++m) {
    fr.aF[m][0] = *(const bf16x8*)(sm + bb + aRow + m * 2048 + kx0);
    fr.aF[m][1] = *(const bf16x8*)(sm + bb + aRow + m * 2048 + kx1);
  }
}
__device__ __forceinline__ void qrB0(const char* sm, int bb, int bRow,
                                     int kx0, int kx1, Frags& fr)
{
#pragma unroll
  for (int n = 0; n < 2; ++n) {
    fr.b0F[n][0] = *(const bf16x8*)(sm + bb + bRow + n * 2048 + kx0);
    fr.b0F[n][1] = *(const bf16x8*)(sm + bb + bRow + n * 2048 + kx1);
  }
}
__device__ __forceinline__ void qrB1(const char* sm, int bb, int bRow,
                                     int kx0, int kx1, Frags& fr)
{
#pragma unroll
  for (int n = 0; n < 2; ++n) {
    fr.b1F[n][0] = *(const bf16x8*)(sm + bb + bRow + (2 + n) * 2048 + kx0);
    fr.b1F[n][1] = *(const bf16x8*)(sm + bb + bRow + (2 + n) * 2048 + kx1);
  }
}
__device__ __forceinline__ void qrA1(const char* sm, int bb, int aRow,
                                     int kx0, int kx1, Frags& fr)
{
#pragma unroll
  for (int m = 0; m < 4; ++m) {
    fr.aG[m][0] = *(const bf16x8*)(sm + bb + aRow + (4 + m) * 2048 + kx0);
    fr.aG[m][1] = *(const bf16x8*)(sm + bb + aRow + (4 + m) * 2048 + kx1);
  }
}

template<int QUAD>
__device__ __forceinline__ void qmfma(f32x4 acc[8][4], Frags& fr)
{
  constexpr int mo = (QUAD >= 2) ? 4 : 0;
  constexpr int no = (QUAD == 1 || QUAD == 2) ? 2 : 0;
  __builtin_amdgcn_s_setprio(1);
#pragma unroll
  for (int m = 0; m < 4; ++m)
#pragma unroll
    for (int n = 0; n < 2; ++n)
#pragma unroll
      for (int ks = 0; ks < 2; ++ks) {
        const bf16x8 av = (QUAD >= 2) ? fr.aG[m][ks] : fr.aF[m][ks];
        const bf16x8 bv = (no == 0) ? fr.b0F[n][ks] : fr.b1F[n][ks];
        acc[mo + m][no + n] =
            __builtin_amdgcn_mfma_f32_16x16x32_bf16(av, bv, acc[mo + m][no + n], 0, 0, 0);
      }
  __builtin_amdgcn_s_setprio(0);
  SB();
}

// EPI modes: 0 = fp32 store (no bias)                      [outproj]
//            1 = bf16 store + col bias                     [QK]
//            2 = bf16 store + row bias                     [VT]
//            3 = bf16 store exp(alpha*v) + fused rowsum    [scores]
//            4 = bf16 store / rsum[row]                    [PV]
template<int EPI, int NT_FAST>
__global__ __launch_bounds__(512, 1)
void gemm256_nt(const unsigned short* __restrict__ A,
                const unsigned short* __restrict__ B,
                void* __restrict__ C,
                const float* __restrict__ bias,
                float alpha, int K,
                long lda, long ldb, long ldc,
                long offA_h, long offA_b,
                long offB_h, long offB_b,
                long offC_h, long offC_b,
                long offBias_h, long offBias_b,
                int MT, int NTt, int nb)
{
  __shared__ __align__(16) char sm[131072];

  const int nwg = gridDim.x;
  const int swz = (blockIdx.x & 7) * (nwg >> 3) + (blockIdx.x >> 3);
  const int per_z = MT * NTt;
  const int z = swz / per_z;
  const int r = swz - z * per_z;
  const int mt = NT_FAST ? (r / NTt) : (r % MT);
  const int nt = NT_FAST ? (r % NTt) : (r / MT);
  const int h = z / nb, bz = z - h * nb;

  const unsigned short* Ablk = A + h * offA_h + bz * offA_b + (long)mt * 256 * lda;
  const unsigned short* Bblk = B + h * offB_h + bz * offB_b + (long)nt * 256 * ldb;

  const int tid  = threadIdx.x;
  const int lane = tid & 63;
  const int w    = tid >> 6;
  const int wr   = w >> 2, wc = w & 3;

  const int rA  = tid >> 3;
  const int cSw = (tid ^ (tid >> 3)) & 7;

  const int aRow = wr * 16384 + (lane & 15) * 128;
  const int bRow = 32768 + (wc >> 1) * 16384 + ((wc & 1) * 64 + (lane & 15)) * 128;
  const int kq = (lane >> 4) * 16, sw = (lane & 7) << 4;
  const int kx0 = kq ^ sw;
  const int kx1 = (64 + kq) ^ sw;

  const int NT = K >> 6;
  const int NIT = NT >> 1;

  f32x4 acc[8][4] = {};
  Frags fr;

  auto stageA = [&](int half, int kt, int region) {
    const unsigned short* g = Ablk + ((long)(half * 128) + rA) * lda + (long)kt * 64 + cSw * 8;
    gload16(g,            sm + region + tid * 16);
    gload16(g + 64 * lda, sm + region + 8192 + tid * 16);
  };
  auto stageB = [&](int half, int kt, int region) {
    const unsigned short* g = Bblk + ((long)(half * 128) + rA) * ldb + (long)kt * 64 + cSw * 8;
    gload16(g,            sm + region + tid * 16);
    gload16(g + 64 * ldb, sm + region + 8192 + tid * 16);
  };

  // group: read buf bb (24 ds_reads, order-pinned), early-stage oth.A<-ktA,
  // counted-lgkm MFMAs, mid-barrier, late-stage bb.B<-ktB, finish, VMC4+SBAR.
  auto group = [&](int bb, int oth, int ktA, int ktB) {
    qrA0(sm, bb, aRow, kx0, kx1, fr);
    qrB0(sm, bb, bRow, kx0, kx1, fr); SB();   // reads 1-12
    qrB1(sm, bb, bRow, kx0, kx1, fr); SB();   // reads 13-16
    qrA1(sm, bb, aRow, kx0, kx1, fr); SB();   // reads 17-24
    stageA(0, ktA, oth);
    stageA(1, ktA, oth + 16384);
    LGKMC(12); qmfma<0>(acc, fr);             // needs reads 1-12
    LGKMC(8);  qmfma<1>(acc, fr);             // needs reads 13-16
    SBAR();                                    // all waves' B reads complete
    stageB(0, ktB, bb + 32768);
    stageB(1, ktB, bb + 49152);
    LGKMC(0);  qmfma<2>(acc, fr); qmfma<3>(acc, fr);
    VMC4();
    SBAR();
  };

  // prologue: buf0.A<-0, buf0.B<-0, buf1.B<-1; drain buf0, keep buf1.B in flight
  stageA(0, 0, 0);
  stageA(1, 0, 16384);
  stageB(0, 0, 32768);
  stageB(1, 0, 49152);
  stageB(0, 1, 65536 + 32768);
  stageB(1, 1, 65536 + 49152);
  VMC4();
  SBAR();

#pragma unroll 1
  for (int it = 0; it < NIT; ++it) {
    const int kt1 = 2 * it + 1;
    const int kt2a = 2 * it + 2, kt2 = kt2a < NT ? kt2a : NT - 1;
    const int kt3a = 2 * it + 3, kt3 = kt3a < NT ? kt3a : NT - 1;

    group(0,     65536, kt1, kt2);   // tile 2it   from buf0
    group(65536, 0,     kt2, kt3);   // tile 2it+1 from buf1
  }

  // epilogue: C/D layout col = lane&15, row = (lane>>4)*4 + j
  const long crow0 = (long)mt * 256 + wr * 128;
  const long ccol0 = (long)nt * 256 + wc * 64;
  const long cbase = h * offC_h + bz * offC_b;
  const float* bptr = bias ? (bias + h * offBias_h + bz * offBias_b) : nullptr;

  float rp[8][4];   // EPI==3: per-(m,j) row partial over this wave's 64 cols

#pragma unroll
  for (int m = 0; m < 8; ++m) {
    float rv4[4];
    if constexpr (EPI == 4) {
#pragma unroll
      for (int j = 0; j < 4; ++j)
        rv4[j] = 1.0f / bptr[crow0 + m * 16 + (lane >> 4) * 4 + j];
    }
#pragma unroll
    for (int n = 0; n < 4; ++n) {
      const long col = ccol0 + n * 16 + (lane & 15);
      const float cb = (EPI == 1) ? bptr[col] : 0.0f;
#pragma unroll
      for (int j = 0; j < 4; ++j) {
        const long row = crow0 + m * 16 + (lane >> 4) * 4 + j;
        float v = acc[m][n][j] * alpha;
        if constexpr (EPI == 1) v += cb;
        if constexpr (EPI == 2) v += bptr[row];
        if constexpr (EPI == 3) v = __expf(v);
        if constexpr (EPI == 4) v *= rv4[j];
        const long idx = cbase + row * ldc + col;
        if constexpr (EPI == 0) {
          ((float*)C)[idx] = v;
        } else {
          const unsigned short hb = f2bf(v);
          ((unsigned short*)C)[idx] = hb;
          if constexpr (EPI == 3) {
            const float vr = bf2f(hb);
            rp[m][j] = (n == 0) ? vr : rp[m][j] + vr;
          }
        }
      }
    }
  }

  if constexpr (EPI == 3) {
    // reduce over the 16-lane col group, one atomicAdd per (row, wave)
#pragma unroll
    for (int m = 0; m < 8; ++m)
#pragma unroll
      for (int j = 0; j < 4; ++j) {
        float s = rp[m][j];
        s += __shfl_xor(s, 1); s += __shfl_xor(s, 2);
        s += __shfl_xor(s, 4); s += __shfl_xor(s, 8);
        if ((lane & 15) == 0) {
          const long row = crow0 + m * 16 + (lane >> 4) * 4 + j;
          atomicAdd((float*)&bptr[row], s);
        }
      }
  }
}

// ---------------- converters / init / epilogue add ----------------------------
// x [s][b][d] fp32 -> Xr [b][s][d] bf16
__global__ __launch_bounds__(256)
void conv_x(const float* __restrict__ in, unsigned short* __restrict__ out)
{
  const long i = (long)blockIdx.x * 256 + threadIdx.x;   // 2M float4
  const long o = i << 2;
  const long b = o >> 20, rem = o & 1048575;
  const long s = rem >> 10, d = rem & 1023;
  const float4 v = *(const float4*)(in + s * 8192 + b * 1024 + d);
  ushort4 u; u.x = f2bf(v.x); u.y = f2bf(v.y); u.z = f2bf(v.z); u.w = f2bf(v.w);
  *(ushort4*)(out + o) = u;
}

__global__ __launch_bounds__(256)
void conv_bf16(const float* __restrict__ in, unsigned short* __restrict__ out, long n4)
{
  const long i = (long)blockIdx.x * 256 + threadIdx.x;
  if (i >= n4) return;
  const float4 v = ((const float4*)in)[i];
  ushort4 o; o.x = f2bf(v.x); o.y = f2bf(v.y); o.z = f2bf(v.z); o.w = f2bf(v.w);
  ((ushort4*)out)[i] = o;
}

// w_out [h][f][e] -> Wob[f][h*1024+e]
__global__ __launch_bounds__(256)
void conv_wout(const float* __restrict__ in, unsigned short* __restrict__ out)
{
  const long i = (long)blockIdx.x * 256 + threadIdx.x;   // 2M float4s
  const long o = i << 2;
  const long f = o >> 13, r = o & 8191;
  const long h = r >> 10, e = r & 1023;
  const float4 v = *(const float4*)(in + h * 1048576 + f * 1024 + e);
  ushort4 u; u.x = f2bf(v.x); u.y = f2bf(v.y); u.z = f2bf(v.z); u.w = f2bf(v.w);
  *(ushort4*)(out + o) = u;
}

__global__ __launch_bounds__(256)
void bias_sum_k(const float* __restrict__ b_out, float* __restrict__ bsum)
{
  const int f = blockIdx.x * 256 + threadIdx.x;
  if (f < 1024) {
    float s = 0.f;
#pragma unroll
    for (int h = 0; h < 8; ++h) s += b_out[h * 1024 + f];
    bsum[f] = s;
  }
}

__global__ __launch_bounds__(256)
void zero_k(float* __restrict__ p, long n4)
{
  const long i = (long)blockIdx.x * 256 + threadIdx.x;
  if (i < n4) ((float4*)p)[i] = make_float4(0.f, 0.f, 0.f, 0.f);
}

// out = p[0] + p[1] + bsum   (2M float4)
__global__ __launch_bounds__(256)
void add_out_k(const float* __restrict__ p, float* __restrict__ out,
               const float* __restrict__ bsum)
{
  const long i = (long)blockIdx.x * 256 + threadIdx.x;
  const float4 a = ((const float4*)p)[i];
  const float4 b = ((const float4*)(p + 8388608))[i];
  const float4 s = ((const float4*)bsum)[i & 255];
  float4 o;
  o.x = a.x + b.x + s.x; o.y = a.y + b.y + s.y;
  o.z = a.z + b.z + s.z; o.w = a.w + b.w + s.w;
  ((float4*)out)[i] = o;
}

// ---------------- launch ------------------------------------------------------
extern "C" void kernel_launch(void* const* d_in, const int* in_sizes, int n_in,
                              void* d_out, int out_size, void* d_ws, size_t ws_size,
                              hipStream_t stream)
{
  const float* x     = (const float*)d_in[0];
  const float* w_in  = (const float*)d_in[1];
  const float* b_in  = (const float*)d_in[2];
  const float* w_out = (const float*)d_in[3];
  const float* b_out = (const float*)d_in[4];
  float* out = (float*)d_out;

  char* ws = (char*)d_ws;
  const long MB = 1ll << 20;
  unsigned short* Xr    = (unsigned short*)(ws);              // 16 MiB [b][s][d]
  unsigned short* Wob   = (unsigned short*)(ws + 16 * MB);    // 16 MiB
  float*          bsum  = (float*)         (ws + 32 * MB);    // 4 KiB
  unsigned short* WbAll = (unsigned short*)(ws + 33 * MB);    // 48 MiB
  unsigned short* Ocat  = (unsigned short*)(ws + 81 * MB);    // 128 MiB
  unsigned short* QKg   = (unsigned short*)(ws + 209 * MB);   // 64 MiB [b*1024+s][hh*2048+u]
  unsigned short* E     = (unsigned short*)(ws + 273 * MB);   // 32 MiB [z][s][t]
  unsigned short* VT    = (unsigned short*)(ws + 305 * MB);   // 32 MiB [z][e][t]
  float*          rsum  = (float*)         (ws + 337 * MB);   // 256 KiB (4 x 16K f32)
  float*          Opart = (float*)QKg;                        // 64 MiB alias (QKg dead)

  dim3 blk(256), blk512(512);

  conv_x    <<<8192,  blk, 0, stream>>>(x, Xr);
  conv_bf16 <<<24576, blk, 0, stream>>>(w_in, WbAll, 6291456);
  conv_wout <<<8192,  blk, 0, stream>>>(w_out, Wob);
  bias_sum_k<<<4,     blk, 0, stream>>>(b_out, bsum);
  zero_k    <<<64,    blk, 0, stream>>>(rsum, 16384);

  for (int g = 0; g < 4; ++g) {
    const long gW = (long)g * 6291456;     // 2 heads x 3072 x 1024
    const long gB = (long)g * 6144;
    float* rs = rsum + (long)g * 16384;

    // QK: z=hh: QKg[b*1024+s][hh*2048 + u] = Xr @ Wqk_hh^T + b_in, u<2048 (q,k)
    gemm256_nt<1,0><<<512, blk512, 0, stream>>>(
        Xr, WbAll + gW, QKg, b_in + gB, 1.0f, 1024,
        1024, 1024, 4096,  0, 0,  3145728, 0,  2048, 0,  3072, 0,  32, 8, 1);

    // VT: z=hh*8+b: VT[z][e][t] = Wv_hh @ Xr_b^T + bv[e] (row bias)
    gemm256_nt<2,0><<<256, blk512, 0, stream>>>(
        WbAll + gW + 2097152, Xr, VT, b_in + gB + 2048, 1.0f, 1024,
        1024, 1024, 1024,  3145728, 0,  0, 1048576,  8388608, 1048576,  3072, 0,  4, 4, 8);

    // scores: z=hh*8+b: E[z][s][t] = exp((Q K^T)/32) bf16 + fused rowsum->rs
    gemm256_nt<3,0><<<256, blk512, 0, stream>>>(
        QKg, QKg + 1024, E, rs, 0.03125f, 1024,
        4096, 4096, 1024,  2048, 4194304,  2048, 4194304,  8388608, 1048576,  8192, 1024,  4, 4, 8);

    // PV: Ocat[(s*8+b)*8192 + (2g+hh)*1024 + e] = (1/rs) * sum_t E VT
    gemm256_nt<4,0><<<256, blk512, 0, stream>>>(
        E, VT, Ocat + (long)g * 2048, rs, 1.0f, 1024,
        1024, 1024, 65536,  8388608, 1048576,  8388608, 1048576,  1024, 8192,  8192, 1024,  4, 4, 8);
  }

  // outproj K-split: Opart[z] = Ocat[:, z*4096:(z+1)*4096] @ Wob[:, same]^T
  gemm256_nt<0,1><<<256, blk512, 0, stream>>>(
      Ocat, Wob, Opart, nullptr, 1.0f, 4096,
      8192, 8192, 1024,  0, 4096,  0, 4096,  0, 8388608,  0, 0,  32, 4, 2);

  add_out_k<<<8192, blk, 0, stream>>>(Opart, out, bsum);
}

// Round 15
// 952.186 us; speedup vs baseline: 1.2766x; 1.2766x over previous
//
#include <hip/hip_runtime.h>
#include <hip/hip_bf16.h>

// MultiAttention: S=1024, B=8, D=1024, H=8
// Round 15: byte-for-byte revert to round 12 (measured best: 950 us, stable).
// R14's 4-wave big-tile needed ~456 VGPRs -> spill VMEM broke the counted
// vmcnt invariant -> NaN. Engine family confirmed at its plateau; this is the
// empirically optimal configuration. ws peak ~338 MiB.

typedef __attribute__((ext_vector_type(8))) __bf16 bf16x8;
typedef __attribute__((ext_vector_type(4))) float f32x4;

__device__ __forceinline__ unsigned short f2bf(float f) {
  union { float f; unsigned u; } x; x.f = f;
  unsigned r = x.u + 0x7fffu + ((x.u >> 16) & 1u);   // RNE
  return (unsigned short)(r >> 16);
}
__device__ __forceinline__ float bf2f(unsigned short u) {
  union { unsigned u; float f; } x; x.u = ((unsigned)u) << 16;
  return x.f;
}

__device__ __forceinline__ void gload16(const void* g, void* l) {
  __builtin_amdgcn_global_load_lds(
      (const __attribute__((address_space(1))) void*)g,
      (__attribute__((address_space(3))) void*)l, 16, 0, 0);
}

#define SBAR()  do { __builtin_amdgcn_sched_barrier(0); __builtin_amdgcn_s_barrier(); \
                     __builtin_amdgcn_sched_barrier(0); } while (0)
#define LGKM0() do { asm volatile("s_waitcnt lgkmcnt(0)" ::: "memory"); \
                     __builtin_amdgcn_sched_barrier(0); } while (0)
#define VMC4()  do { asm volatile("s_waitcnt vmcnt(4)" ::: "memory"); \
                     __builtin_amdgcn_sched_barrier(0); } while (0)

// ================= 256x256 8-phase NT GEMM (round-6/10 core) ==================
struct Frags { bf16x8 aF[4][2]; bf16x8 b0F[2][2]; bf16x8 b1F[2][2]; };

template<int QUAD>
__device__ __forceinline__ void qreads(const char* sm, int bb, int aRow, int bRow,
                                       int kx0, int kx1, Frags& fr)
{
  if constexpr (QUAD == 0) {
#pragma unroll
    for (int m = 0; m < 4; ++m) {
      fr.aF[m][0] = *(const bf16x8*)(sm + bb + aRow + m * 2048 + kx0);
      fr.aF[m][1] = *(const bf16x8*)(sm + bb + aRow + m * 2048 + kx1);
    }
#pragma unroll
    for (int n = 0; n < 2; ++n) {
      fr.b0F[n][0] = *(const bf16x8*)(sm + bb + bRow + n * 2048 + kx0);
      fr.b0F[n][1] = *(const bf16x8*)(sm + bb + bRow + n * 2048 + kx1);
    }
  } else if constexpr (QUAD == 1) {
#pragma unroll
    for (int n = 0; n < 2; ++n) {
      fr.b1F[n][0] = *(const bf16x8*)(sm + bb + bRow + (2 + n) * 2048 + kx0);
      fr.b1F[n][1] = *(const bf16x8*)(sm + bb + bRow + (2 + n) * 2048 + kx1);
    }
  } else if constexpr (QUAD == 2) {
#pragma unroll
    for (int m = 0; m < 4; ++m) {
      fr.aF[m][0] = *(const bf16x8*)(sm + bb + aRow + (4 + m) * 2048 + kx0);
      fr.aF[m][1] = *(const bf16x8*)(sm + bb + aRow + (4 + m) * 2048 + kx1);
    }
  }
}

template<int QUAD>
__device__ __forceinline__ void qmfma(f32x4 acc[8][4], Frags& fr)
{
  constexpr int mo = (QUAD >= 2) ? 4 : 0;
  constexpr int no = (QUAD == 1 || QUAD == 2) ? 2 : 0;
  __builtin_amdgcn_s_setprio(1);
#pragma unroll
  for (int m = 0; m < 4; ++m)
#pragma unroll
    for (int n = 0; n < 2; ++n)
#pragma unroll
      for (int ks = 0; ks < 2; ++ks) {
        const bf16x8 bv = (no == 0) ? fr.b0F[n][ks] : fr.b1F[n][ks];
        acc[mo + m][no + n] =
            __builtin_amdgcn_mfma_f32_16x16x32_bf16(fr.aF[m][ks], bv, acc[mo + m][no + n], 0, 0, 0);
      }
  __builtin_amdgcn_s_setprio(0);
  __builtin_amdgcn_sched_barrier(0);
}

// EPI modes: 0 = fp32 store (no bias)                      [outproj]
//            1 = bf16 store + col bias                     [QK]
//            2 = bf16 store + row bias                     [VT]
//            3 = bf16 store exp(alpha*v) + fused rowsum    [scores]
//            4 = bf16 store / rsum[row]                    [PV]
template<int EPI, int NT_FAST>
__global__ __launch_bounds__(512, 1)
void gemm256_nt(const unsigned short* __restrict__ A,
                const unsigned short* __restrict__ B,
                void* __restrict__ C,
                const float* __restrict__ bias,
                float alpha, int K,
                long lda, long ldb, long ldc,
                long offA_h, long offA_b,
                long offB_h, long offB_b,
                long offC_h, long offC_b,
                long offBias_h, long offBias_b,
                int MT, int NTt, int nb)
{
  __shared__ __align__(16) char sm[131072];

  const int nwg = gridDim.x;
  const int swz = (blockIdx.x & 7) * (nwg >> 3) + (blockIdx.x >> 3);
  const int per_z = MT * NTt;
  const int z = swz / per_z;
  const int r = swz - z * per_z;
  const int mt = NT_FAST ? (r / NTt) : (r % MT);
  const int nt = NT_FAST ? (r % NTt) : (r / MT);
  const int h = z / nb, bz = z - h * nb;

  const unsigned short* Ablk = A + h * offA_h + bz * offA_b + (long)mt * 256 * lda;
  const unsigned short* Bblk = B + h * offB_h + bz * offB_b + (long)nt * 256 * ldb;

  const int tid  = threadIdx.x;
  const int lane = tid & 63;
  const int w    = tid >> 6;
  const int wr   = w >> 2, wc = w & 3;

  const int rA  = tid >> 3;
  const int cSw = (tid ^ (tid >> 3)) & 7;

  const int aRow = wr * 16384 + (lane & 15) * 128;
  const int bRow = 32768 + (wc >> 1) * 16384 + ((wc & 1) * 64 + (lane & 15)) * 128;
  const int kq = (lane >> 4) * 16, sw = (lane & 7) << 4;
  const int kx0 = kq ^ sw;
  const int kx1 = (64 + kq) ^ sw;

  const int NT = K >> 6;
  const int NIT = NT >> 1;

  f32x4 acc[8][4] = {};
  Frags fr;

  auto stageA = [&](int half, int kt, int region) {
    const unsigned short* g = Ablk + ((long)(half * 128) + rA) * lda + (long)kt * 64 + cSw * 8;
    gload16(g,            sm + region + tid * 16);
    gload16(g + 64 * lda, sm + region + 8192 + tid * 16);
  };
  auto stageB = [&](int half, int kt, int region) {
    const unsigned short* g = Bblk + ((long)(half * 128) + rA) * ldb + (long)kt * 64 + cSw * 8;
    gload16(g,            sm + region + tid * 16);
    gload16(g + 64 * ldb, sm + region + 8192 + tid * 16);
  };

  stageA(0, 0, 0);
  stageA(1, 0, 16384);
  stageB(0, 0, 32768);
  stageB(1, 0, 49152);
  stageB(0, 1, 65536 + 32768);
  stageB(1, 1, 65536 + 49152);
  VMC4();
  SBAR();

#pragma unroll 1
  for (int it = 0; it < NIT; ++it) {
    const int kt1 = 2 * it + 1;
    const int kt2a = 2 * it + 2, kt2 = kt2a < NT ? kt2a : NT - 1;
    const int kt3a = 2 * it + 3, kt3 = kt3a < NT ? kt3a : NT - 1;

    qreads<0>(sm, 0, aRow, bRow, kx0, kx1, fr);
    stageA(0, kt1, 65536);
    SBAR(); LGKM0(); qmfma<0>(acc, fr); SBAR();

    qreads<1>(sm, 0, aRow, bRow, kx0, kx1, fr);
    stageA(1, kt1, 65536 + 16384);
    SBAR(); LGKM0(); qmfma<1>(acc, fr); SBAR();

    qreads<2>(sm, 0, aRow, bRow, kx0, kx1, fr);
    stageB(0, kt2, 32768);
    SBAR(); LGKM0(); qmfma<2>(acc, fr); SBAR();

    stageB(1, kt2, 49152);
    SBAR(); LGKM0(); qmfma<3>(acc, fr);
    VMC4();
    SBAR();

    qreads<0>(sm, 65536, aRow, bRow, kx0, kx1, fr);
    stageA(0, kt2, 0);
    SBAR(); LGKM0(); qmfma<0>(acc, fr); SBAR();

    qreads<1>(sm, 65536, aRow, bRow, kx0, kx1, fr);
    stageA(1, kt2, 16384);
    SBAR(); LGKM0(); qmfma<1>(acc, fr); SBAR();

    qreads<2>(sm, 65536, aRow, bRow, kx0, kx1, fr);
    stageB(0, kt3, 65536 + 32768);
    SBAR(); LGKM0(); qmfma<2>(acc, fr); SBAR();

    stageB(1, kt3, 65536 + 49152);
    SBAR(); LGKM0(); qmfma<3>(acc, fr);
    VMC4();
    SBAR();
  }

  // epilogue: C/D layout col = lane&15, row = (lane>>4)*4 + j
  const long crow0 = (long)mt * 256 + wr * 128;
  const long ccol0 = (long)nt * 256 + wc * 64;
  const long cbase = h * offC_h + bz * offC_b;
  const float* bptr = bias ? (bias + h * offBias_h + bz * offBias_b) : nullptr;

  float rp[8][4];   // EPI==3: per-(m,j) row partial over this wave's 64 cols

#pragma unroll
  for (int m = 0; m < 8; ++m) {
    float rv4[4];
    if constexpr (EPI == 4) {
#pragma unroll
      for (int j = 0; j < 4; ++j)
        rv4[j] = 1.0f / bptr[crow0 + m * 16 + (lane >> 4) * 4 + j];
    }
#pragma unroll
    for (int n = 0; n < 4; ++n) {
      const long col = ccol0 + n * 16 + (lane & 15);
      const float cb = (EPI == 1) ? bptr[col] : 0.0f;
#pragma unroll
      for (int j = 0; j < 4; ++j) {
        const long row = crow0 + m * 16 + (lane >> 4) * 4 + j;
        float v = acc[m][n][j] * alpha;
        if constexpr (EPI == 1) v += cb;
        if constexpr (EPI == 2) v += bptr[row];
        if constexpr (EPI == 3) v = __expf(v);
        if constexpr (EPI == 4) v *= rv4[j];
        const long idx = cbase + row * ldc + col;
        if constexpr (EPI == 0) {
          ((float*)C)[idx] = v;
        } else {
          const unsigned short hb = f2bf(v);
          ((unsigned short*)C)[idx] = hb;
          if constexpr (EPI == 3) {
            const float vr = bf2f(hb);
            rp[m][j] = (n == 0) ? vr : rp[m][j] + vr;
          }
        }
      }
    }
  }

  if constexpr (EPI == 3) {
    // reduce over the 16-lane col group, one atomicAdd per (row, wave)
#pragma unroll
    for (int m = 0; m < 8; ++m)
#pragma unroll
      for (int j = 0; j < 4; ++j) {
        float s = rp[m][j];
        s += __shfl_xor(s, 1); s += __shfl_xor(s, 2);
        s += __shfl_xor(s, 4); s += __shfl_xor(s, 8);
        if ((lane & 15) == 0) {
          const long row = crow0 + m * 16 + (lane >> 4) * 4 + j;
          atomicAdd((float*)&bptr[row], s);
        }
      }
  }
}

// ---------------- converters / init / epilogue add ----------------------------
// x [s][b][d] fp32 -> Xr [b][s][d] bf16
__global__ __launch_bounds__(256)
void conv_x(const float* __restrict__ in, unsigned short* __restrict__ out)
{
  const long i = (long)blockIdx.x * 256 + threadIdx.x;   // 2M float4
  const long o = i << 2;
  const long b = o >> 20, rem = o & 1048575;
  const long s = rem >> 10, d = rem & 1023;
  const float4 v = *(const float4*)(in + s * 8192 + b * 1024 + d);
  ushort4 u; u.x = f2bf(v.x); u.y = f2bf(v.y); u.z = f2bf(v.z); u.w = f2bf(v.w);
  *(ushort4*)(out + o) = u;
}

__global__ __launch_bounds__(256)
void conv_bf16(const float* __restrict__ in, unsigned short* __restrict__ out, long n4)
{
  const long i = (long)blockIdx.x * 256 + threadIdx.x;
  if (i >= n4) return;
  const float4 v = ((const float4*)in)[i];
  ushort4 o; o.x = f2bf(v.x); o.y = f2bf(v.y); o.z = f2bf(v.z); o.w = f2bf(v.w);
  ((ushort4*)out)[i] = o;
}

// w_out [h][f][e] -> Wob[f][h*1024+e]
__global__ __launch_bounds__(256)
void conv_wout(const float* __restrict__ in, unsigned short* __restrict__ out)
{
  const long i = (long)blockIdx.x * 256 + threadIdx.x;   // 2M float4s
  const long o = i << 2;
  const long f = o >> 13, r = o & 8191;
  const long h = r >> 10, e = r & 1023;
  const float4 v = *(const float4*)(in + h * 1048576 + f * 1024 + e);
  ushort4 u; u.x = f2bf(v.x); u.y = f2bf(v.y); u.z = f2bf(v.z); u.w = f2bf(v.w);
  *(ushort4*)(out + o) = u;
}

__global__ __launch_bounds__(256)
void bias_sum_k(const float* __restrict__ b_out, float* __restrict__ bsum)
{
  const int f = blockIdx.x * 256 + threadIdx.x;
  if (f < 1024) {
    float s = 0.f;
#pragma unroll
    for (int h = 0; h < 8; ++h) s += b_out[h * 1024 + f];
    bsum[f] = s;
  }
}

__global__ __launch_bounds__(256)
void zero_k(float* __restrict__ p, long n4)
{
  const long i = (long)blockIdx.x * 256 + threadIdx.x;
  if (i < n4) ((float4*)p)[i] = make_float4(0.f, 0.f, 0.f, 0.f);
}

// out = p[0] + p[1] + bsum   (2M float4)
__global__ __launch_bounds__(256)
void add_out_k(const float* __restrict__ p, float* __restrict__ out,
               const float* __restrict__ bsum)
{
  const long i = (long)blockIdx.x * 256 + threadIdx.x;
  const float4 a = ((const float4*)p)[i];
  const float4 b = ((const float4*)(p + 8388608))[i];
  const float4 s = ((const float4*)bsum)[i & 255];
  float4 o;
  o.x = a.x + b.x + s.x; o.y = a.y + b.y + s.y;
  o.z = a.z + b.z + s.z; o.w = a.w + b.w + s.w;
  ((float4*)out)[i] = o;
}

// ---------------- launch ------------------------------------------------------
extern "C" void kernel_launch(void* const* d_in, const int* in_sizes, int n_in,
                              void* d_out, int out_size, void* d_ws, size_t ws_size,
                              hipStream_t stream)
{
  const float* x     = (const float*)d_in[0];
  const float* w_in  = (const float*)d_in[1];
  const float* b_in  = (const float*)d_in[2];
  const float* w_out = (const float*)d_in[3];
  const float* b_out = (const float*)d_in[4];
  float* out = (float*)d_out;

  char* ws = (char*)d_ws;
  const long MB = 1ll << 20;
  unsigned short* Xr    = (unsigned short*)(ws);              // 16 MiB [b][s][d]
  unsigned short* Wob   = (unsigned short*)(ws + 16 * MB);    // 16 MiB
  float*          bsum  = (float*)         (ws + 32 * MB);    // 4 KiB
  unsigned short* WbAll = (unsigned short*)(ws + 33 * MB);    // 48 MiB
  unsigned short* Ocat  = (unsigned short*)(ws + 81 * MB);    // 128 MiB
  unsigned short* QKg   = (unsigned short*)(ws + 209 * MB);   // 64 MiB [b*1024+s][hh*2048+u]
  unsigned short* E     = (unsigned short*)(ws + 273 * MB);   // 32 MiB [z][s][t]
  unsigned short* VT    = (unsigned short*)(ws + 305 * MB);   // 32 MiB [z][e][t]
  float*          rsum  = (float*)         (ws + 337 * MB);   // 256 KiB (4 x 16K f32)
  float*          Opart = (float*)QKg;                        // 64 MiB alias (QKg dead)

  dim3 blk(256), blk512(512);

  conv_x    <<<8192,  blk, 0, stream>>>(x, Xr);
  conv_bf16 <<<24576, blk, 0, stream>>>(w_in, WbAll, 6291456);
  conv_wout <<<8192,  blk, 0, stream>>>(w_out, Wob);
  bias_sum_k<<<4,     blk, 0, stream>>>(b_out, bsum);
  zero_k    <<<64,    blk, 0, stream>>>(rsum, 16384);

  for (int g = 0; g < 4; ++g) {
    const long gW = (long)g * 6291456;     // 2 heads x 3072 x 1024
    const long gB = (long)g * 6144;
    float* rs = rsum + (long)g * 16384;

    // QK: z=hh: QKg[b*1024+s][hh*2048 + u] = Xr @ Wqk_hh^T + b_in, u<2048 (q,k)
    gemm256_nt<1,0><<<512, blk512, 0, stream>>>(
        Xr, WbAll + gW, QKg, b_in + gB, 1.0f, 1024,
        1024, 1024, 4096,  0, 0,  3145728, 0,  2048, 0,  3072, 0,  32, 8, 1);

    // VT: z=hh*8+b: VT[z][e][t] = Wv_hh @ Xr_b^T + bv[e] (row bias)
    gemm256_nt<2,0><<<256, blk512, 0, stream>>>(
        WbAll + gW + 2097152, Xr, VT, b_in + gB + 2048, 1.0f, 1024,
        1024, 1024, 1024,  3145728, 0,  0, 1048576,  8388608, 1048576,  3072, 0,  4, 4, 8);

    // scores: z=hh*8+b: E[z][s][t] = exp((Q K^T)/32) bf16 + fused rowsum->rs
    gemm256_nt<3,0><<<256, blk512, 0, stream>>>(
        QKg, QKg + 1024, E, rs, 0.03125f, 1024,
        4096, 4096, 1024,  2048, 4194304,  2048, 4194304,  8388608, 1048576,  8192, 1024,  4, 4, 8);

    // PV: Ocat[(s*8+b)*8192 + (2g+hh)*1024 + e] = (1/rs) * sum_t E VT
    gemm256_nt<4,0><<<256, blk512, 0, stream>>>(
        E, VT, Ocat + (long)g * 2048, rs, 1.0f, 1024,
        1024, 1024, 65536,  8388608, 1048576,  8388608, 1048576,  1024, 8192,  8192, 1024,  4, 4, 8);
  }

  // outproj K-split: Opart[z] = Ocat[:, z*4096:(z+1)*4096] @ Wob[:, same]^T
  gemm256_nt<0,1><<<256, blk512, 0, stream>>>(
      Ocat, Wob, Opart, nullptr, 1.0f, 4096,
      8192, 8192, 1024,  0, 4096,  0, 4096,  0, 8388608,  0, 0,  32, 4, 2);

  add_out_k<<<8192, blk, 0, stream>>>(Opart, out, bsum);
}

// Round 16
// 922.470 us; speedup vs baseline: 1.3178x; 1.0322x over previous
//
#include <hip/hip_runtime.h>
#include <hip/hip_bf16.h>

// MultiAttention: S=1024, B=8, D=1024, H=8
// Round 16: r12/r15 engine byte-identical; dataflow regrouped into 2 super-
// groups of 4 heads to cut dispatch boundaries (27 -> 17) and run bigger
// grids (QK 1024 blocks, VT/scores/PV 512). Aliases: VT reuses QKg region
// (dead after scores); Wob converted late into dead E region. ws peak 362 MiB.

typedef __attribute__((ext_vector_type(8))) __bf16 bf16x8;
typedef __attribute__((ext_vector_type(4))) float f32x4;

__device__ __forceinline__ unsigned short f2bf(float f) {
  union { float f; unsigned u; } x; x.f = f;
  unsigned r = x.u + 0x7fffu + ((x.u >> 16) & 1u);   // RNE
  return (unsigned short)(r >> 16);
}
__device__ __forceinline__ float bf2f(unsigned short u) {
  union { unsigned u; float f; } x; x.u = ((unsigned)u) << 16;
  return x.f;
}

__device__ __forceinline__ void gload16(const void* g, void* l) {
  __builtin_amdgcn_global_load_lds(
      (const __attribute__((address_space(1))) void*)g,
      (__attribute__((address_space(3))) void*)l, 16, 0, 0);
}

#define SBAR()  do { __builtin_amdgcn_sched_barrier(0); __builtin_amdgcn_s_barrier(); \
                     __builtin_amdgcn_sched_barrier(0); } while (0)
#define LGKM0() do { asm volatile("s_waitcnt lgkmcnt(0)" ::: "memory"); \
                     __builtin_amdgcn_sched_barrier(0); } while (0)
#define VMC4()  do { asm volatile("s_waitcnt vmcnt(4)" ::: "memory"); \
                     __builtin_amdgcn_sched_barrier(0); } while (0)

// ================= 256x256 8-phase NT GEMM (round-12 core, unchanged) =========
struct Frags { bf16x8 aF[4][2]; bf16x8 b0F[2][2]; bf16x8 b1F[2][2]; };

template<int QUAD>
__device__ __forceinline__ void qreads(const char* sm, int bb, int aRow, int bRow,
                                       int kx0, int kx1, Frags& fr)
{
  if constexpr (QUAD == 0) {
#pragma unroll
    for (int m = 0; m < 4; ++m) {
      fr.aF[m][0] = *(const bf16x8*)(sm + bb + aRow + m * 2048 + kx0);
      fr.aF[m][1] = *(const bf16x8*)(sm + bb + aRow + m * 2048 + kx1);
    }
#pragma unroll
    for (int n = 0; n < 2; ++n) {
      fr.b0F[n][0] = *(const bf16x8*)(sm + bb + bRow + n * 2048 + kx0);
      fr.b0F[n][1] = *(const bf16x8*)(sm + bb + bRow + n * 2048 + kx1);
    }
  } else if constexpr (QUAD == 1) {
#pragma unroll
    for (int n = 0; n < 2; ++n) {
      fr.b1F[n][0] = *(const bf16x8*)(sm + bb + bRow + (2 + n) * 2048 + kx0);
      fr.b1F[n][1] = *(const bf16x8*)(sm + bb + bRow + (2 + n) * 2048 + kx1);
    }
  } else if constexpr (QUAD == 2) {
#pragma unroll
    for (int m = 0; m < 4; ++m) {
      fr.aF[m][0] = *(const bf16x8*)(sm + bb + aRow + (4 + m) * 2048 + kx0);
      fr.aF[m][1] = *(const bf16x8*)(sm + bb + aRow + (4 + m) * 2048 + kx1);
    }
  }
}

template<int QUAD>
__device__ __forceinline__ void qmfma(f32x4 acc[8][4], Frags& fr)
{
  constexpr int mo = (QUAD >= 2) ? 4 : 0;
  constexpr int no = (QUAD == 1 || QUAD == 2) ? 2 : 0;
  __builtin_amdgcn_s_setprio(1);
#pragma unroll
  for (int m = 0; m < 4; ++m)
#pragma unroll
    for (int n = 0; n < 2; ++n)
#pragma unroll
      for (int ks = 0; ks < 2; ++ks) {
        const bf16x8 bv = (no == 0) ? fr.b0F[n][ks] : fr.b1F[n][ks];
        acc[mo + m][no + n] =
            __builtin_amdgcn_mfma_f32_16x16x32_bf16(fr.aF[m][ks], bv, acc[mo + m][no + n], 0, 0, 0);
      }
  __builtin_amdgcn_s_setprio(0);
  __builtin_amdgcn_sched_barrier(0);
}

// EPI modes: 0 = fp32 store (no bias)                      [outproj]
//            1 = bf16 store + col bias                     [QK]
//            2 = bf16 store + row bias                     [VT]
//            3 = bf16 store exp(alpha*v) + fused rowsum    [scores]
//            4 = bf16 store / rsum[row]                    [PV]
template<int EPI, int NT_FAST>
__global__ __launch_bounds__(512, 1)
void gemm256_nt(const unsigned short* __restrict__ A,
                const unsigned short* __restrict__ B,
                void* __restrict__ C,
                const float* __restrict__ bias,
                float alpha, int K,
                long lda, long ldb, long ldc,
                long offA_h, long offA_b,
                long offB_h, long offB_b,
                long offC_h, long offC_b,
                long offBias_h, long offBias_b,
                int MT, int NTt, int nb)
{
  __shared__ __align__(16) char sm[131072];

  const int nwg = gridDim.x;
  const int swz = (blockIdx.x & 7) * (nwg >> 3) + (blockIdx.x >> 3);
  const int per_z = MT * NTt;
  const int z = swz / per_z;
  const int r = swz - z * per_z;
  const int mt = NT_FAST ? (r / NTt) : (r % MT);
  const int nt = NT_FAST ? (r % NTt) : (r / MT);
  const int h = z / nb, bz = z - h * nb;

  const unsigned short* Ablk = A + h * offA_h + bz * offA_b + (long)mt * 256 * lda;
  const unsigned short* Bblk = B + h * offB_h + bz * offB_b + (long)nt * 256 * ldb;

  const int tid  = threadIdx.x;
  const int lane = tid & 63;
  const int w    = tid >> 6;
  const int wr   = w >> 2, wc = w & 3;

  const int rA  = tid >> 3;
  const int cSw = (tid ^ (tid >> 3)) & 7;

  const int aRow = wr * 16384 + (lane & 15) * 128;
  const int bRow = 32768 + (wc >> 1) * 16384 + ((wc & 1) * 64 + (lane & 15)) * 128;
  const int kq = (lane >> 4) * 16, sw = (lane & 7) << 4;
  const int kx0 = kq ^ sw;
  const int kx1 = (64 + kq) ^ sw;

  const int NT = K >> 6;
  const int NIT = NT >> 1;

  f32x4 acc[8][4] = {};
  Frags fr;

  auto stageA = [&](int half, int kt, int region) {
    const unsigned short* g = Ablk + ((long)(half * 128) + rA) * lda + (long)kt * 64 + cSw * 8;
    gload16(g,            sm + region + tid * 16);
    gload16(g + 64 * lda, sm + region + 8192 + tid * 16);
  };
  auto stageB = [&](int half, int kt, int region) {
    const unsigned short* g = Bblk + ((long)(half * 128) + rA) * ldb + (long)kt * 64 + cSw * 8;
    gload16(g,            sm + region + tid * 16);
    gload16(g + 64 * ldb, sm + region + 8192 + tid * 16);
  };

  stageA(0, 0, 0);
  stageA(1, 0, 16384);
  stageB(0, 0, 32768);
  stageB(1, 0, 49152);
  stageB(0, 1, 65536 + 32768);
  stageB(1, 1, 65536 + 49152);
  VMC4();
  SBAR();

#pragma unroll 1
  for (int it = 0; it < NIT; ++it) {
    const int kt1 = 2 * it + 1;
    const int kt2a = 2 * it + 2, kt2 = kt2a < NT ? kt2a : NT - 1;
    const int kt3a = 2 * it + 3, kt3 = kt3a < NT ? kt3a : NT - 1;

    qreads<0>(sm, 0, aRow, bRow, kx0, kx1, fr);
    stageA(0, kt1, 65536);
    SBAR(); LGKM0(); qmfma<0>(acc, fr); SBAR();

    qreads<1>(sm, 0, aRow, bRow, kx0, kx1, fr);
    stageA(1, kt1, 65536 + 16384);
    SBAR(); LGKM0(); qmfma<1>(acc, fr); SBAR();

    qreads<2>(sm, 0, aRow, bRow, kx0, kx1, fr);
    stageB(0, kt2, 32768);
    SBAR(); LGKM0(); qmfma<2>(acc, fr); SBAR();

    stageB(1, kt2, 49152);
    SBAR(); LGKM0(); qmfma<3>(acc, fr);
    VMC4();
    SBAR();

    qreads<0>(sm, 65536, aRow, bRow, kx0, kx1, fr);
    stageA(0, kt2, 0);
    SBAR(); LGKM0(); qmfma<0>(acc, fr); SBAR();

    qreads<1>(sm, 65536, aRow, bRow, kx0, kx1, fr);
    stageA(1, kt2, 16384);
    SBAR(); LGKM0(); qmfma<1>(acc, fr); SBAR();

    qreads<2>(sm, 65536, aRow, bRow, kx0, kx1, fr);
    stageB(0, kt3, 65536 + 32768);
    SBAR(); LGKM0(); qmfma<2>(acc, fr); SBAR();

    stageB(1, kt3, 65536 + 49152);
    SBAR(); LGKM0(); qmfma<3>(acc, fr);
    VMC4();
    SBAR();
  }

  // epilogue: C/D layout col = lane&15, row = (lane>>4)*4 + j
  const long crow0 = (long)mt * 256 + wr * 128;
  const long ccol0 = (long)nt * 256 + wc * 64;
  const long cbase = h * offC_h + bz * offC_b;
  const float* bptr = bias ? (bias + h * offBias_h + bz * offBias_b) : nullptr;

  float rp[8][4];   // EPI==3: per-(m,j) row partial over this wave's 64 cols

#pragma unroll
  for (int m = 0; m < 8; ++m) {
    float rv4[4];
    if constexpr (EPI == 4) {
#pragma unroll
      for (int j = 0; j < 4; ++j)
        rv4[j] = 1.0f / bptr[crow0 + m * 16 + (lane >> 4) * 4 + j];
    }
#pragma unroll
    for (int n = 0; n < 4; ++n) {
      const long col = ccol0 + n * 16 + (lane & 15);
      const float cb = (EPI == 1) ? bptr[col] : 0.0f;
#pragma unroll
      for (int j = 0; j < 4; ++j) {
        const long row = crow0 + m * 16 + (lane >> 4) * 4 + j;
        float v = acc[m][n][j] * alpha;
        if constexpr (EPI == 1) v += cb;
        if constexpr (EPI == 2) v += bptr[row];
        if constexpr (EPI == 3) v = __expf(v);
        if constexpr (EPI == 4) v *= rv4[j];
        const long idx = cbase + row * ldc + col;
        if constexpr (EPI == 0) {
          ((float*)C)[idx] = v;
        } else {
          const unsigned short hb = f2bf(v);
          ((unsigned short*)C)[idx] = hb;
          if constexpr (EPI == 3) {
            const float vr = bf2f(hb);
            rp[m][j] = (n == 0) ? vr : rp[m][j] + vr;
          }
        }
      }
    }
  }

  if constexpr (EPI == 3) {
    // reduce over the 16-lane col group, one atomicAdd per (row, wave)
#pragma unroll
    for (int m = 0; m < 8; ++m)
#pragma unroll
      for (int j = 0; j < 4; ++j) {
        float s = rp[m][j];
        s += __shfl_xor(s, 1); s += __shfl_xor(s, 2);
        s += __shfl_xor(s, 4); s += __shfl_xor(s, 8);
        if ((lane & 15) == 0) {
          const long row = crow0 + m * 16 + (lane >> 4) * 4 + j;
          atomicAdd((float*)&bptr[row], s);
        }
      }
  }
}

// ---------------- converters / init / epilogue add ----------------------------
// x [s][b][d] fp32 -> Xr [b][s][d] bf16
__global__ __launch_bounds__(256)
void conv_x(const float* __restrict__ in, unsigned short* __restrict__ out)
{
  const long i = (long)blockIdx.x * 256 + threadIdx.x;   // 2M float4
  const long o = i << 2;
  const long b = o >> 20, rem = o & 1048575;
  const long s = rem >> 10, d = rem & 1023;
  const float4 v = *(const float4*)(in + s * 8192 + b * 1024 + d);
  ushort4 u; u.x = f2bf(v.x); u.y = f2bf(v.y); u.z = f2bf(v.z); u.w = f2bf(v.w);
  *(ushort4*)(out + o) = u;
}

__global__ __launch_bounds__(256)
void conv_bf16(const float* __restrict__ in, unsigned short* __restrict__ out, long n4)
{
  const long i = (long)blockIdx.x * 256 + threadIdx.x;
  if (i >= n4) return;
  const float4 v = ((const float4*)in)[i];
  ushort4 o; o.x = f2bf(v.x); o.y = f2bf(v.y); o.z = f2bf(v.z); o.w = f2bf(v.w);
  ((ushort4*)out)[i] = o;
}

// w_out [h][f][e] -> Wob[f][h*1024+e]
__global__ __launch_bounds__(256)
void conv_wout(const float* __restrict__ in, unsigned short* __restrict__ out)
{
  const long i = (long)blockIdx.x * 256 + threadIdx.x;   // 2M float4s
  const long o = i << 2;
  const long f = o >> 13, r = o & 8191;
  const long h = r >> 10, e = r & 1023;
  const float4 v = *(const float4*)(in + h * 1048576 + f * 1024 + e);
  ushort4 u; u.x = f2bf(v.x); u.y = f2bf(v.y); u.z = f2bf(v.z); u.w = f2bf(v.w);
  *(ushort4*)(out + o) = u;
}

__global__ __launch_bounds__(256)
void bias_sum_k(const float* __restrict__ b_out, float* __restrict__ bsum)
{
  const int f = blockIdx.x * 256 + threadIdx.x;
  if (f < 1024) {
    float s = 0.f;
#pragma unroll
    for (int h = 0; h < 8; ++h) s += b_out[h * 1024 + f];
    bsum[f] = s;
  }
}

__global__ __launch_bounds__(256)
void zero_k(float* __restrict__ p, long n4)
{
  const long i = (long)blockIdx.x * 256 + threadIdx.x;
  if (i < n4) ((float4*)p)[i] = make_float4(0.f, 0.f, 0.f, 0.f);
}

// out = p[0] + p[1] + bsum   (2M float4)
__global__ __launch_bounds__(256)
void add_out_k(const float* __restrict__ p, float* __restrict__ out,
               const float* __restrict__ bsum)
{
  const long i = (long)blockIdx.x * 256 + threadIdx.x;
  const float4 a = ((const float4*)p)[i];
  const float4 b = ((const float4*)(p + 8388608))[i];
  const float4 s = ((const float4*)bsum)[i & 255];
  float4 o;
  o.x = a.x + b.x + s.x; o.y = a.y + b.y + s.y;
  o.z = a.z + b.z + s.z; o.w = a.w + b.w + s.w;
  ((float4*)out)[i] = o;
}

// ---------------- launch ------------------------------------------------------
extern "C" void kernel_launch(void* const* d_in, const int* in_sizes, int n_in,
                              void* d_out, int out_size, void* d_ws, size_t ws_size,
                              hipStream_t stream)
{
  const float* x     = (const float*)d_in[0];
  const float* w_in  = (const float*)d_in[1];
  const float* b_in  = (const float*)d_in[2];
  const float* w_out = (const float*)d_in[3];
  const float* b_out = (const float*)d_in[4];
  float* out = (float*)d_out;

  char* ws = (char*)d_ws;
  const long MB = 1ll << 20;
  unsigned short* Xr   = (unsigned short*)(ws);              // 16 MiB [b][s][d]
  float*          bsum = (float*)         (ws + 16 * MB);    // 4 KiB
  float*          rsum = (float*)         (ws + 17 * MB);    // 256 KiB (2 x 32K f32)
  unsigned short* Wbg  = (unsigned short*)(ws + 18 * MB);    // 24 MiB (4 heads QKV)
  unsigned short* Ocat = (unsigned short*)(ws + 42 * MB);    // 128 MiB -> 170
  unsigned short* QKg  = (unsigned short*)(ws + 170 * MB);   // 128 MiB [b*1024+s][hh*2048+u] -> 298
  unsigned short* E    = (unsigned short*)(ws + 298 * MB);   // 64 MiB [z][s][t] -> 362
  // aliases (stream-ordered lifetimes):
  unsigned short* VTb  = QKg;                  // VT [z][e][t] 64 MiB; QKg dead after scores
  float*          Opart = (float*)QKg;         // 64 MiB fp32; after middle
  unsigned short* Wob  = E;                    // 16 MiB; E dead after last PV

  dim3 blk(256), blk512(512);

  conv_x    <<<8192, blk, 0, stream>>>(x, Xr);
  bias_sum_k<<<4,    blk, 0, stream>>>(b_out, bsum);
  zero_k    <<<64,   blk, 0, stream>>>(rsum, 16384);

  for (int G = 0; G < 2; ++G) {
    const long gW = (long)G * 12582912;    // 4 heads x 3072 x 1024 fp32 elems
    const long gB = (long)G * 12288;       // 4 heads x 3072 bias
    float* rs = rsum + (long)G * 32768;

    // weights for heads 4G..4G+3: [12288][1024] bf16
    conv_bf16<<<12288, blk, 0, stream>>>(w_in + gW, Wbg, 3145728);

    // QK: z=hh (4): QKg[b*1024+s][hh*2048+u] = Xr @ Wqk_hh^T + b_in  (1024 blocks)
    gemm256_nt<1,0><<<1024, blk512, 0, stream>>>(
        Xr, Wbg, QKg, b_in + gB, 1.0f, 1024,
        1024, 1024, 8192,  0, 0,  3145728, 0,  2048, 0,  3072, 0,  32, 8, 1);

    // scores: z=hh*8+b (32): E[z][s][t] = exp((Q K^T)/32) bf16 + fused rowsum->rs
    gemm256_nt<3,0><<<512, blk512, 0, stream>>>(
        QKg, QKg + 1024, E, rs, 0.03125f, 1024,
        8192, 8192, 1024,  2048, 8388608,  2048, 8388608,  8388608, 1048576,  8192, 1024,  4, 4, 8);

    // VT (into QKg region — QKg dead after scores): VT[z][e][t] = Wv_hh @ Xr_b^T + bv[e]
    gemm256_nt<2,0><<<512, blk512, 0, stream>>>(
        Wbg + 2097152, Xr, VTb, b_in + gB + 2048, 1.0f, 1024,
        1024, 1024, 1024,  3145728, 0,  0, 1048576,  8388608, 1048576,  3072, 0,  4, 4, 8);

    // PV: Ocat[(s*8+b)*8192 + (4G+hh)*1024 + e] = (1/rs) * sum_t E VT
    gemm256_nt<4,0><<<512, blk512, 0, stream>>>(
        E, VTb, Ocat + (long)G * 4096, rs, 1.0f, 1024,
        1024, 1024, 65536,  8388608, 1048576,  8388608, 1048576,  1024, 8192,  8192, 1024,  4, 4, 8);
  }

  // late conversion into dead E region
  conv_wout<<<8192, blk, 0, stream>>>(w_out, Wob);

  // outproj K-split: Opart[z] = Ocat[:, z*4096:(z+1)*4096] @ Wob[:, same]^T
  gemm256_nt<0,1><<<256, blk512, 0, stream>>>(
      Ocat, Wob, Opart, nullptr, 1.0f, 4096,
      8192, 8192, 1024,  0, 4096,  0, 4096,  0, 8388608,  0, 0,  32, 4, 2);

  add_out_k<<<8192, blk, 0, stream>>>(Opart, out, bsum);
}